// Round 8
// baseline (15993.262 us; speedup 1.0000x reference)
//
#include <hip/hip_runtime.h>
#include <math.h>

#define LSEQ 256
#define HID 256
#define H2 512
#define H3 768
#define H8 2048

typedef __attribute__((ext_vector_type(8))) short short8;
typedef __attribute__((ext_vector_type(4))) float floatx4;
typedef __attribute__((ext_vector_type(16))) unsigned int uvec16;

__device__ __forceinline__ float sigmoidf_(float x) { return 1.f / (1.f + __expf(-x)); }
__device__ __forceinline__ unsigned short f2bf(float f) {
    unsigned int u = __float_as_uint(f);
    u = (u + 0x7FFFu + ((u >> 16) & 1u)) >> 16;
    return (unsigned short)u;
}
__device__ __forceinline__ float bf2f(unsigned short h) {
    return __uint_as_float(((unsigned int)h) << 16);
}
__device__ __forceinline__ float bflo(unsigned int w) {
    return __uint_as_float(w << 16);
}
__device__ __forceinline__ float bfhi(unsigned int w) {
    return __uint_as_float(w & 0xFFFF0000u);
}

// ---------------- embed ----------------
__global__ void embed_kernel(const int* __restrict__ question,
                             const int* __restrict__ article,
                             const float* __restrict__ emb,
                             float* __restrict__ xemb) {
    int gid = blockIdx.x * 256 + threadIdx.x;   // 128*256*256
    int d = gid & 255;
    int rl = gid >> 8;
    int l = rl & 255;
    int stream = rl >> 8;
    int id;
    if (stream < 64) {
        int b = stream >> 3, o = (stream & 7) >> 1;
        id = question[(b * 4 + o) * 256 + l];
    } else {
        id = article[(stream - 64) * 256 + l];
    }
    xemb[(size_t)gid] = emb[(size_t)id * 256 + d];
}

// ---------------- MFMA bf16 GEMM ----------------
__global__ __launch_bounds__(256)
void gemm_mfma_bf16(const float* __restrict__ A, const float* __restrict__ B,
                    const float* __restrict__ bias, unsigned short* __restrict__ C,
                    int M, int N, int K) {
    __shared__ unsigned short At[128][40];
    __shared__ unsigned short Bt[128][40];
    int tid = threadIdx.x;
    int m0 = blockIdx.x * 128, n0 = blockIdx.y * 128;
    int l = tid & 63, w = tid >> 6;
    int wm = (w & 1) * 64, wn = (w >> 1) * 64;
    int lr = l & 15, koff = (l >> 4) * 8;
    int srow = tid >> 1, scol = (tid & 1) * 16;
    floatx4 acc[4][4];
#pragma unroll
    for (int i = 0; i < 4; i++)
#pragma unroll
        for (int j = 0; j < 4; j++) acc[i][j] = (floatx4){0.f, 0.f, 0.f, 0.f};
    for (int k0 = 0; k0 < K; k0 += 32) {
        const float* ap = A + (size_t)(m0 + srow) * K + k0 + scol;
        const float* bp = B + (size_t)(n0 + srow) * K + k0 + scol;
        float av[16], bv[16];
        *(float4*)&av[0]  = *(const float4*)(ap);
        *(float4*)&av[4]  = *(const float4*)(ap + 4);
        *(float4*)&av[8]  = *(const float4*)(ap + 8);
        *(float4*)&av[12] = *(const float4*)(ap + 12);
        *(float4*)&bv[0]  = *(const float4*)(bp);
        *(float4*)&bv[4]  = *(const float4*)(bp + 4);
        *(float4*)&bv[8]  = *(const float4*)(bp + 8);
        *(float4*)&bv[12] = *(const float4*)(bp + 12);
        unsigned int aw[8], bw[8];
#pragma unroll
        for (int i = 0; i < 8; i++) {
            aw[i] = (unsigned int)f2bf(av[2 * i]) | ((unsigned int)f2bf(av[2 * i + 1]) << 16);
            bw[i] = (unsigned int)f2bf(bv[2 * i]) | ((unsigned int)f2bf(bv[2 * i + 1]) << 16);
        }
        __syncthreads();
        *(uint4*)&At[srow][scol]     = *(uint4*)&aw[0];
        *(uint4*)&At[srow][scol + 8] = *(uint4*)&aw[4];
        *(uint4*)&Bt[srow][scol]     = *(uint4*)&bw[0];
        *(uint4*)&Bt[srow][scol + 8] = *(uint4*)&bw[4];
        __syncthreads();
        short8 af[4], bf[4];
#pragma unroll
        for (int i = 0; i < 4; i++) {
            af[i] = *(const short8*)&At[wm + i * 16 + lr][koff];
            bf[i] = *(const short8*)&Bt[wn + i * 16 + lr][koff];
        }
#pragma unroll
        for (int i = 0; i < 4; i++)
#pragma unroll
            for (int j = 0; j < 4; j++)
                acc[i][j] = __builtin_amdgcn_mfma_f32_16x16x32_bf16(af[i], bf[j], acc[i][j], 0, 0, 0);
    }
    int quad = l >> 4;
#pragma unroll
    for (int i = 0; i < 4; i++) {
#pragma unroll
        for (int j = 0; j < 4; j++) {
            int n = n0 + wn + j * 16 + lr;
            float bs = bias[n];
#pragma unroll
            for (int r = 0; r < 4; r++) {
                int m = m0 + wm + i * 16 + quad * 4 + r;
                C[(size_t)m * N + n] = f2bf(acc[i][j][r] + bs);
            }
        }
    }
}

// ---------------- whh pack to [d][chunk(32)][col(768)][i(4)] of bf16 pairs ----------------
// pair p = 4c+i covers whh k = 2p, 2p+1 for column col. One uint4 per (c,col).
__global__ void pack_whh4(const float* __restrict__ whh, unsigned int* __restrict__ wq) {
    int idx = blockIdx.x * 256 + threadIdx.x;   // 196,608 total
    int d = idx / 98304, r = idx % 98304;
    int c = r / 3072, r2 = r % 3072;
    int col = r2 >> 2, i = r2 & 3;
    int p = 4 * c + i;
    float lo = whh[d * 196608 + col * 256 + 2 * p];
    float hi = whh[d * 196608 + col * 256 + 2 * p + 1];
    wq[idx] = (unsigned int)f2bf(lo) | ((unsigned int)f2bf(hi) << 16);
}

// ---------------- Path A': register-resident weights, occupancy pinned ----------------
#define WLOAD(WV, VOFF)                                              \
    { _Pragma("unroll")                                              \
      for (int c_ = 0; c_ < 4; c_++) {                               \
        uint4 q_ = Wq[((VOFF) * 4 + c_) * 768 + col];                \
        WV[4 * c_ + 0] = q_.x; WV[4 * c_ + 1] = q_.y;                \
        WV[4 * c_ + 2] = q_.z; WV[4 * c_ + 3] = q_.w;                \
      } }

#define WCHUNK(WV, VOFF)                                             \
    { _Pragma("unroll")                                              \
      for (int j_ = 0; j_ < 8; j_++) {                               \
        float4 hv = hs4[(VOFF) * 8 + j_];                            \
        unsigned int u0 = WV[2 * j_];                                \
        unsigned int u1 = WV[2 * j_ + 1];                            \
        acc += bflo(u0) * hv.x + bfhi(u0) * hv.y                     \
             + bflo(u1) * hv.z + bfhi(u1) * hv.w;                    \
      } }

__global__ __launch_bounds__(768)
__attribute__((amdgpu_waves_per_eu(3, 3)))
void gru_scan_vec(const unsigned short* __restrict__ gi_f, const unsigned short* __restrict__ gi_b,
                  const unsigned int* __restrict__ wpk, const float* __restrict__ bhh,
                  float* __restrict__ out) {
    int blk = blockIdx.x;
    int d = blk & 1, s = blk >> 1;
    const unsigned short* gi = (d ? gi_b : gi_f) + (size_t)s * LSEQ * H3;
    int col = threadIdx.x;          // 0..767
    const uint4* Wq = (const uint4*)(wpk + d * 98304);
    uvec16 W0, W1, W2, W3, W4, W5, W6, W7;
    WLOAD(W0, 0) WLOAD(W1, 1) WLOAD(W2, 2) WLOAD(W3, 3)
    WLOAD(W4, 4) WLOAD(W5, 5) WLOAD(W6, 6) WLOAD(W7, 7)
    float bcol = bhh[d * 768 + col];
    __shared__ float hs[HID];
    __shared__ float g[H3];
    __shared__ float gn[HID];
    if (col < HID) hs[col] = 0.f;
    float hreg = 0.f;
    __syncthreads();
    const float4* hs4 = (const float4*)hs;
    for (int step = 0; step < LSEQ; ++step) {
        int t = d ? (LSEQ - 1 - step) : step;
        float acc = bcol;
        WCHUNK(W0, 0) WCHUNK(W1, 1) WCHUNK(W2, 2) WCHUNK(W3, 3)
        WCHUNK(W4, 4) WCHUNK(W5, 5) WCHUNK(W6, 6) WCHUNK(W7, 7)
        float giv = bf2f(gi[(size_t)t * H3 + col]);
        if (col < 512) g[col] = giv + acc;            // r,z pre-act
        else { g[col] = acc; gn[col - 512] = giv; }   // hn pre-act, gi_n
        __syncthreads();
        if (col < HID) {
            float r = sigmoidf_(g[col]);
            float z = sigmoidf_(g[col + 256]);
            float n = tanhf(gn[col] + r * g[col + 512]);
            float hnew = (1.f - z) * n + z * hreg;
            hreg = hnew;
            hs[col] = hnew;
            out[((size_t)s * LSEQ + t) * H2 + d * HID + col] = hnew;
        }
        __syncthreads();
    }
}

// ---------------- Path B': streamed weights, 768 threads, uint4 loads ----------------
__global__ __launch_bounds__(768)
void gru_scan_stream(const unsigned short* __restrict__ gi_f, const unsigned short* __restrict__ gi_b,
                     const unsigned int* __restrict__ wpk, const float* __restrict__ bhh,
                     float* __restrict__ out) {
    int blk = blockIdx.x;
    int d = blk & 1, s = blk >> 1;
    const unsigned short* gi = (d ? gi_b : gi_f) + (size_t)s * LSEQ * H3;
    int col = threadIdx.x;          // 0..767
    const uint4* Wq = (const uint4*)(wpk + d * 98304);
    float bcol = bhh[d * 768 + col];
    __shared__ float hs[HID];
    __shared__ float g[H3];
    __shared__ float gn[HID];
    if (col < HID) hs[col] = 0.f;
    float hreg = 0.f;
    __syncthreads();
    const float4* hs4 = (const float4*)hs;
    for (int step = 0; step < LSEQ; ++step) {
        int t = d ? (LSEQ - 1 - step) : step;
        float acc = bcol;
#pragma unroll
        for (int c = 0; c < 32; c++) {
            uint4 wv = Wq[c * 768 + col];      // coalesced 16B/lane from L2
            float4 h0 = hs4[2 * c], h1 = hs4[2 * c + 1];
            acc += bflo(wv.x) * h0.x + bfhi(wv.x) * h0.y
                 + bflo(wv.y) * h0.z + bfhi(wv.y) * h0.w
                 + bflo(wv.z) * h1.x + bfhi(wv.z) * h1.y
                 + bflo(wv.w) * h1.z + bfhi(wv.w) * h1.w;
        }
        float giv = bf2f(gi[(size_t)t * H3 + col]);
        if (col < 512) g[col] = giv + acc;
        else { g[col] = acc; gn[col - 512] = giv; }
        __syncthreads();
        if (col < HID) {
            float r = sigmoidf_(g[col]);
            float z = sigmoidf_(g[col + 256]);
            float n = tanhf(gn[col] + r * g[col + 512]);
            float hnew = (1.f - z) * n + z * hreg;
            hreg = hnew;
            hs[col] = hnew;
            out[((size_t)s * LSEQ + t) * H2 + d * HID + col] = hnew;
        }
        __syncthreads();
    }
}

// ---------------- bidaf helpers (fp32, unchanged) ----------------
__global__ void cwqw_kernel(const float* __restrict__ c, const float* __restrict__ q,
                            const float* __restrict__ w,
                            float* __restrict__ cw, float* __restrict__ qw) {
    int row = blockIdx.x;
    int lane = threadIdx.x;
    const float* src; const float* wv; float* dst; int r;
    if (row < 16384) { src = c; wv = w; dst = cw; r = row; }
    else { src = q; wv = w + 512; dst = qw; r = row - 16384; }
    const float* p = src + (size_t)r * H2;
    float acc = 0.f;
    for (int j = lane; j < H2; j += 64) acc += p[j] * wv[j];
    for (int off = 32; off; off >>= 1) acc += __shfl_down(acc, off);
    if (lane == 0) dst[r] = acc;
}

__global__ __launch_bounds__(256)
void smat_kernel(const float* __restrict__ c, const float* __restrict__ q,
                 const float* __restrict__ w2, const float* __restrict__ bvec,
                 const float* __restrict__ cw, const float* __restrict__ qw,
                 float* __restrict__ smat) {
    int b = blockIdx.z;
    int m0 = blockIdx.x * 64, n0 = blockIdx.y * 64;
    const float* A = c + (size_t)b * LSEQ * H2;
    const float* B = q + (size_t)b * LSEQ * H2;
    __shared__ float As[16][64];
    __shared__ float Bs[16][64];
    int tid = threadIdx.x;
    int lr = tid >> 2, lc = (tid & 3) * 4;
    int tm = (tid >> 4) * 4, tn = (tid & 15) * 4;
    float acc[4][4];
#pragma unroll
    for (int i = 0; i < 4; i++)
#pragma unroll
        for (int j = 0; j < 4; j++) acc[i][j] = 0.f;
    for (int k0 = 0; k0 < H2; k0 += 16) {
        float4 av = *(const float4*)(A + (size_t)(m0 + lr) * H2 + k0 + lc);
        float4 wv = *(const float4*)(w2 + k0 + lc);
        As[lc + 0][lr] = av.x * wv.x; As[lc + 1][lr] = av.y * wv.y;
        As[lc + 2][lr] = av.z * wv.z; As[lc + 3][lr] = av.w * wv.w;
        float4 bv = *(const float4*)(B + (size_t)(n0 + lr) * H2 + k0 + lc);
        Bs[lc + 0][lr] = bv.x; Bs[lc + 1][lr] = bv.y; Bs[lc + 2][lr] = bv.z; Bs[lc + 3][lr] = bv.w;
        __syncthreads();
#pragma unroll
        for (int kk = 0; kk < 16; kk++) {
            float4 a0 = *(const float4*)&As[kk][tm];
            float4 b0 = *(const float4*)&Bs[kk][tn];
            float a[4] = {a0.x, a0.y, a0.z, a0.w};
            float bb4[4] = {b0.x, b0.y, b0.z, b0.w};
#pragma unroll
            for (int i = 0; i < 4; i++)
#pragma unroll
                for (int j = 0; j < 4; j++) acc[i][j] += a[i] * bb4[j];
        }
        __syncthreads();
    }
    float bsum = bvec[0] + bvec[1] + bvec[2];
#pragma unroll
    for (int i = 0; i < 4; i++) {
        int m = m0 + tm + i;
        float cwv = cw[b * LSEQ + m];
        float4 o;
        o.x = acc[i][0] + cwv + qw[b * LSEQ + n0 + tn + 0] + bsum;
        o.y = acc[i][1] + cwv + qw[b * LSEQ + n0 + tn + 1] + bsum;
        o.z = acc[i][2] + cwv + qw[b * LSEQ + n0 + tn + 2] + bsum;
        o.w = acc[i][3] + cwv + qw[b * LSEQ + n0 + tn + 3] + bsum;
        *(float4*)(smat + ((size_t)b * LSEQ + m) * LSEQ + n0 + tn) = o;
    }
}

__global__ void softmax_kernel(float* __restrict__ smat, float* __restrict__ rowmax) {
    int row = blockIdx.x;
    int lane = threadIdx.x;
    float* p = smat + (size_t)row * LSEQ;
    float v[4];
    float mx = -1e30f;
#pragma unroll
    for (int j = 0; j < 4; j++) { v[j] = p[lane + j * 64]; mx = fmaxf(mx, v[j]); }
    for (int off = 32; off; off >>= 1) mx = fmaxf(mx, __shfl_down(mx, off));
    mx = __shfl(mx, 0);
    float sum = 0.f;
#pragma unroll
    for (int j = 0; j < 4; j++) { v[j] = __expf(v[j] - mx); sum += v[j]; }
    for (int off = 32; off; off >>= 1) sum += __shfl_down(sum, off);
    sum = __shfl(sum, 0);
    float inv = 1.f / sum;
#pragma unroll
    for (int j = 0; j < 4; j++) p[lane + j * 64] = v[j] * inv;
    if (lane == 0) rowmax[row] = mx;
}

__global__ void bb_kernel(const float* __restrict__ rowmax, float* __restrict__ bb) {
    int b = blockIdx.x; int t = threadIdx.x;
    __shared__ float red[256];
    float v = rowmax[b * LSEQ + t];
    red[t] = v; __syncthreads();
    for (int s = 128; s; s >>= 1) { if (t < s) red[t] = fmaxf(red[t], red[t + s]); __syncthreads(); }
    float mx = red[0]; __syncthreads();
    float e = __expf(v - mx);
    red[t] = e; __syncthreads();
    for (int s = 128; s; s >>= 1) { if (t < s) red[t] += red[t + s]; __syncthreads(); }
    bb[b * LSEQ + t] = e / red[0];
}

__global__ void q2c_kernel(const float* __restrict__ bb, const float* __restrict__ c,
                           float* __restrict__ q2c) {
    int b = blockIdx.x; int t = threadIdx.x;
    float a0 = 0.f, a1 = 0.f;
    for (int i = 0; i < LSEQ; i++) {
        float w = bb[b * LSEQ + i];
        const float* row = c + ((size_t)b * LSEQ + i) * H2;
        a0 += w * row[t];
        a1 += w * row[t + 256];
    }
    q2c[b * H2 + t] = a0;
    q2c[b * H2 + t + 256] = a1;
}

__global__ __launch_bounds__(256)
void c2q_fixup(const float* __restrict__ amat, const float* __restrict__ q,
               const float* __restrict__ c, float* __restrict__ att, int add) {
    int b = blockIdx.z;
    int m0 = blockIdx.x * 64, n0 = blockIdx.y * 64;
    const float* A = amat + (size_t)b * LSEQ * LSEQ;
    const float* B = q + (size_t)b * LSEQ * H2;
    __shared__ float As[16][64];
    __shared__ float Bs[16][64];
    int tid = threadIdx.x;
    int lr = tid >> 2, lc = (tid & 3) * 4;
    int br = tid >> 4, bc = (tid & 15) * 4;
    int tm = (tid >> 4) * 4, tn = (tid & 15) * 4;
    float acc[4][4];
#pragma unroll
    for (int i = 0; i < 4; i++)
#pragma unroll
        for (int j = 0; j < 4; j++) acc[i][j] = 0.f;
    for (int k0 = 0; k0 < LSEQ; k0 += 16) {
        float4 av = *(const float4*)(A + (size_t)(m0 + lr) * LSEQ + k0 + lc);
        As[lc + 0][lr] = av.x; As[lc + 1][lr] = av.y; As[lc + 2][lr] = av.z; As[lc + 3][lr] = av.w;
        float4 bv = *(const float4*)(B + (size_t)(k0 + br) * H2 + n0 + bc);
        *(float4*)&Bs[br][bc] = bv;
        __syncthreads();
#pragma unroll
        for (int kk = 0; kk < 16; kk++) {
            float4 a0 = *(const float4*)&As[kk][tm];
            float4 b0 = *(const float4*)&Bs[kk][tn];
            float a[4] = {a0.x, a0.y, a0.z, a0.w};
            float bb4[4] = {b0.x, b0.y, b0.z, b0.w};
#pragma unroll
            for (int i = 0; i < 4; i++)
#pragma unroll
                for (int j = 0; j < 4; j++) acc[i][j] += a[i] * bb4[j];
        }
        __syncthreads();
    }
#pragma unroll
    for (int i = 0; i < 4; i++) {
        int row = b * LSEQ + m0 + tm + i;
        float4 cv = *(const float4*)(c + (size_t)row * H2 + n0 + tn);
        float4 v1, v2;
        v1.x = fmaxf(acc[i][0], 0.f); v1.y = fmaxf(acc[i][1], 0.f);
        v1.z = fmaxf(acc[i][2], 0.f); v1.w = fmaxf(acc[i][3], 0.f);
        v2.x = fmaxf(cv.x * acc[i][0], 0.f); v2.y = fmaxf(cv.y * acc[i][1], 0.f);
        v2.z = fmaxf(cv.z * acc[i][2], 0.f); v2.w = fmaxf(cv.w * acc[i][3], 0.f);
        float* p1 = att + (size_t)row * H8 + 512 + n0 + tn;
        float* p2 = att + (size_t)row * H8 + 1024 + n0 + tn;
        if (add) {
            float4 o1 = *(float4*)p1, o2 = *(float4*)p2;
            o1.x += v1.x; o1.y += v1.y; o1.z += v1.z; o1.w += v1.w;
            o2.x += v2.x; o2.y += v2.y; o2.z += v2.z; o2.w += v2.w;
            *(float4*)p1 = o1; *(float4*)p2 = o2;
        } else {
            *(float4*)p1 = v1; *(float4*)p2 = v2;
        }
    }
}

__global__ void fixup03(const float* __restrict__ c, const float* __restrict__ q2c,
                        float* __restrict__ att, int add) {
    int row = blockIdx.x;
    int t = threadIdx.x;
    int b = row >> 8;
    float* o = att + (size_t)row * H8;
#pragma unroll
    for (int rep = 0; rep < 2; rep++) {
        int d = t + rep * 256;
        float cv = c[(size_t)row * H2 + d];
        float qv = q2c[b * H2 + d];
        float v0 = fmaxf(cv, 0.f);
        float v3 = fmaxf(cv * qv, 0.f);
        if (add) { o[d] += v0; o[d + 1536] += v3; }
        else     { o[d]  = v0; o[d + 1536]  = v3; }
    }
}

// ---------------- final rank reduce ----------------
__global__ void reduce1_kernel(const float* __restrict__ s, const float* __restrict__ rw,
                               float* __restrict__ part) {
    int bo = blockIdx.x;
    int p = blockIdx.y;
    int t = threadIdx.x;
    const float* s0 = s + (size_t)(2 * bo) * 524288;
    const float* s1 = s0 + 524288;
    size_t base = (size_t)p * 65536;
    float acc = 0.f;
    for (int j = t; j < 65536; j += 256) {
        size_t m = base + j;
        acc += rw[m] * fmaxf(s0[m], s1[m]);
    }
    __shared__ float red[256];
    red[t] = acc; __syncthreads();
    for (int ss = 128; ss; ss >>= 1) { if (t < ss) red[t] += red[t + ss]; __syncthreads(); }
    if (t == 0) part[bo * 8 + p] = red[0];
}

__global__ void reduce2_kernel(const float* __restrict__ part, const float* __restrict__ rb,
                               float* __restrict__ out) {
    int t = threadIdx.x;
    float a = rb[0];
    for (int p = 0; p < 8; p++) a += part[t * 8 + p];
    out[t] = a;
}

extern "C" void kernel_launch(void* const* d_in, const int* in_sizes, int n_in,
                              void* d_out, int out_size, void* d_ws, size_t ws_size,
                              hipStream_t stream) {
    const int* question = (const int*)d_in[0];
    const int* article  = (const int*)d_in[1];
    const float* emb    = (const float*)d_in[2];
    const float* g1_wih = (const float*)d_in[3];
    const float* g1_whh = (const float*)d_in[4];
    const float* g1_bih = (const float*)d_in[5];
    const float* g1_bhh = (const float*)d_in[6];
    const float* g2_wih = (const float*)d_in[7];
    const float* g2_whh = (const float*)d_in[8];
    const float* g2_bih = (const float*)d_in[9];
    const float* g2_bhh = (const float*)d_in[10];
    const float* b1_w   = (const float*)d_in[11];
    const float* b1_b   = (const float*)d_in[12];
    const float* b2_w   = (const float*)d_in[13];
    const float* b2_b   = (const float*)d_in[14];
    const float* rank_w = (const float*)d_in[15];
    const float* rank_b = (const float*)d_in[16];
    float* ws = (float*)d_ws;
    float* out = (float*)d_out;

    // ---- workspace layout (fp32 slots) — peak 224 MiB (proven budget) ----
    float*          HBUF  = ws;
    float*          ATT   = ws + 16777216;
    float*          XEMB  = ws + 16777216;
    unsigned short* GI1B  = (unsigned short*)(ws + 25165824);  // 2 dirs x 32768 x 768 bf16
    unsigned int*   WPK1  = (unsigned int*)(ws + 50331648);    // 196608 uints
    float*          SMAT1 = ws + 50331648;
    float*          S1    = ws + 54525952;
    unsigned short* GI2B  = (unsigned short*)ws;               // 2 dirs x 16384 x 768 bf16
    unsigned int*   WPK2  = (unsigned int*)(ws + 12582912);
    float*          AX2   = ws + 50331648;
    float*          SMAT2 = ws;
    float*          S2    = ws + 4194304;

    // 1. embed + pack whh1
    embed_kernel<<<32768, 256, 0, stream>>>(question, article, emb, XEMB);
    pack_whh4<<<768, 256, 0, stream>>>(g1_whh, WPK1);

    // 2. GRU1 input gates via MFMA: per dir, M=32768 N=768 K=256
    for (int d = 0; d < 2; d++) {
        gemm_mfma_bf16<<<dim3(256, 6), 256, 0, stream>>>(
            XEMB, g1_wih + (size_t)d * 196608, g1_bih + d * 768,
            GI1B + (size_t)d * 32768 * 768, 32768, 768, 256);
    }
    // 3. GRU1 scan — Path A' (register-resident weights, occupancy pinned 3,3)
    gru_scan_vec<<<256, 768, 0, stream>>>(GI1B, GI1B + (size_t)32768 * 768, WPK1, g1_bhh, HBUF);

    float* QH = HBUF;
    float* AH = HBUF + (size_t)64 * 256 * 512;

    // 4. BiDAF1: c=QH, q=AH -> ATT (set)
    {
        float* CW = S1, *QW = S1 + 16384, *RM = S1 + 32768, *BBv = S1 + 49152, *Q2C = S1 + 65536;
        cwqw_kernel<<<32768, 64, 0, stream>>>(QH, AH, b1_w, CW, QW);
        smat_kernel<<<dim3(4, 4, 64), 256, 0, stream>>>(QH, AH, b1_w + 1024, b1_b, CW, QW, SMAT1);
        softmax_kernel<<<16384, 64, 0, stream>>>(SMAT1, RM);
        bb_kernel<<<64, 256, 0, stream>>>(RM, BBv);
        q2c_kernel<<<64, 256, 0, stream>>>(BBv, QH, Q2C);
        fixup03<<<16384, 256, 0, stream>>>(QH, Q2C, ATT, 0);
        c2q_fixup<<<dim3(4, 8, 64), 256, 0, stream>>>(SMAT1, AH, QH, ATT, 0);
    }

    // pack whh2 (HBUF dead, region free)
    pack_whh4<<<768, 256, 0, stream>>>(g2_whh, WPK2);

    // 5. GRU2 input gates via MFMA: per dir, M=16384 N=768 K=2048
    for (int d = 0; d < 2; d++) {
        gemm_mfma_bf16<<<dim3(128, 6), 256, 0, stream>>>(
            ATT, g2_wih + (size_t)d * 1572864, g2_bih + d * 768,
            GI2B + (size_t)d * 16384 * 768, 16384, 768, 2048);
    }
    // 6. GRU2 scan — Path B' (streamed uint4 weights, 12 waves)
    gru_scan_stream<<<128, 768, 0, stream>>>(GI2B, GI2B + (size_t)16384 * 768, WPK2, g2_bhh, AX2);

    // 7. BiDAF2: c=q=AX2 -> ATT (accumulate)
    {
        float* CW = S2, *QW = S2 + 16384, *RM = S2 + 32768, *BBv = S2 + 49152, *Q2C = S2 + 65536;
        cwqw_kernel<<<32768, 64, 0, stream>>>(AX2, AX2, b2_w, CW, QW);
        smat_kernel<<<dim3(4, 4, 64), 256, 0, stream>>>(AX2, AX2, b2_w + 1024, b2_b, CW, QW, SMAT2);
        softmax_kernel<<<16384, 64, 0, stream>>>(SMAT2, RM);
        bb_kernel<<<64, 256, 0, stream>>>(RM, BBv);
        q2c_kernel<<<64, 256, 0, stream>>>(BBv, AX2, Q2C);
        fixup03<<<16384, 256, 0, stream>>>(AX2, Q2C, ATT, 1);
        c2q_fixup<<<dim3(4, 8, 64), 256, 0, stream>>>(SMAT2, AX2, AX2, ATT, 1);
    }

    // 8. rank reduce
    float* PART = S2 + 98304;
    reduce1_kernel<<<dim3(32, 8), 256, 0, stream>>>(ATT, rank_w, PART);
    reduce2_kernel<<<1, 32, 0, stream>>>(PART, rank_b, out);
}

// Round 9
// 4199.255 us; speedup vs baseline: 3.8086x; 3.8086x over previous
//
#include <hip/hip_runtime.h>
#include <math.h>

#define LSEQ 256
#define HID 256
#define H2 512
#define H3 768
#define H8 2048

typedef __attribute__((ext_vector_type(8))) short short8;
typedef __attribute__((ext_vector_type(4))) float floatx4;

__device__ __forceinline__ float sigmoidf_(float x) { return 1.f / (1.f + __expf(-x)); }
__device__ __forceinline__ unsigned short f2bf(float f) {
    unsigned int u = __float_as_uint(f);
    u = (u + 0x7FFFu + ((u >> 16) & 1u)) >> 16;
    return (unsigned short)u;
}
__device__ __forceinline__ float bf2f(unsigned short h) {
    return __uint_as_float(((unsigned int)h) << 16);
}
__device__ __forceinline__ float bflo(unsigned int w) {
    return __uint_as_float(w << 16);
}
__device__ __forceinline__ float bfhi(unsigned int w) {
    return __uint_as_float(w & 0xFFFF0000u);
}

// ---------------- embed ----------------
__global__ void embed_kernel(const int* __restrict__ question,
                             const int* __restrict__ article,
                             const float* __restrict__ emb,
                             float* __restrict__ xemb) {
    int gid = blockIdx.x * 256 + threadIdx.x;   // 128*256*256
    int d = gid & 255;
    int rl = gid >> 8;
    int l = rl & 255;
    int stream = rl >> 8;
    int id;
    if (stream < 64) {
        int b = stream >> 3, o = (stream & 7) >> 1;
        id = question[(b * 4 + o) * 256 + l];
    } else {
        id = article[(stream - 64) * 256 + l];
    }
    xemb[(size_t)gid] = emb[(size_t)id * 256 + d];
}

// ---------------- MFMA bf16 GEMM ----------------
__global__ __launch_bounds__(256)
void gemm_mfma_bf16(const float* __restrict__ A, const float* __restrict__ B,
                    const float* __restrict__ bias, unsigned short* __restrict__ C,
                    int M, int N, int K) {
    __shared__ unsigned short At[128][40];
    __shared__ unsigned short Bt[128][40];
    int tid = threadIdx.x;
    int m0 = blockIdx.x * 128, n0 = blockIdx.y * 128;
    int l = tid & 63, w = tid >> 6;
    int wm = (w & 1) * 64, wn = (w >> 1) * 64;
    int lr = l & 15, koff = (l >> 4) * 8;
    int srow = tid >> 1, scol = (tid & 1) * 16;
    floatx4 acc[4][4];
#pragma unroll
    for (int i = 0; i < 4; i++)
#pragma unroll
        for (int j = 0; j < 4; j++) acc[i][j] = (floatx4){0.f, 0.f, 0.f, 0.f};
    for (int k0 = 0; k0 < K; k0 += 32) {
        const float* ap = A + (size_t)(m0 + srow) * K + k0 + scol;
        const float* bp = B + (size_t)(n0 + srow) * K + k0 + scol;
        float av[16], bv[16];
        *(float4*)&av[0]  = *(const float4*)(ap);
        *(float4*)&av[4]  = *(const float4*)(ap + 4);
        *(float4*)&av[8]  = *(const float4*)(ap + 8);
        *(float4*)&av[12] = *(const float4*)(ap + 12);
        *(float4*)&bv[0]  = *(const float4*)(bp);
        *(float4*)&bv[4]  = *(const float4*)(bp + 4);
        *(float4*)&bv[8]  = *(const float4*)(bp + 8);
        *(float4*)&bv[12] = *(const float4*)(bp + 12);
        unsigned int aw[8], bw[8];
#pragma unroll
        for (int i = 0; i < 8; i++) {
            aw[i] = (unsigned int)f2bf(av[2 * i]) | ((unsigned int)f2bf(av[2 * i + 1]) << 16);
            bw[i] = (unsigned int)f2bf(bv[2 * i]) | ((unsigned int)f2bf(bv[2 * i + 1]) << 16);
        }
        __syncthreads();
        *(uint4*)&At[srow][scol]     = *(uint4*)&aw[0];
        *(uint4*)&At[srow][scol + 8] = *(uint4*)&aw[4];
        *(uint4*)&Bt[srow][scol]     = *(uint4*)&bw[0];
        *(uint4*)&Bt[srow][scol + 8] = *(uint4*)&bw[4];
        __syncthreads();
        short8 af[4], bf[4];
#pragma unroll
        for (int i = 0; i < 4; i++) {
            af[i] = *(const short8*)&At[wm + i * 16 + lr][koff];
            bf[i] = *(const short8*)&Bt[wn + i * 16 + lr][koff];
        }
#pragma unroll
        for (int i = 0; i < 4; i++)
#pragma unroll
            for (int j = 0; j < 4; j++)
                acc[i][j] = __builtin_amdgcn_mfma_f32_16x16x32_bf16(af[i], bf[j], acc[i][j], 0, 0, 0);
    }
    int quad = l >> 4;
#pragma unroll
    for (int i = 0; i < 4; i++) {
#pragma unroll
        for (int j = 0; j < 4; j++) {
            int n = n0 + wn + j * 16 + lr;
            float bs = bias[n];
#pragma unroll
            for (int r = 0; r < 4; r++) {
                int m = m0 + wm + i * 16 + quad * 4 + r;
                C[(size_t)m * N + n] = f2bf(acc[i][j][r] + bs);
            }
        }
    }
}

// ---------------- whh pack: wpk[d][k2][col] = pack_bf16(whh[d][col][2k2], whh[d][col][2k2+1]) ----------------
__global__ void pack_whh_k2(const float* __restrict__ whh, unsigned int* __restrict__ wpk) {
    int idx = blockIdx.x * 256 + threadIdx.x;   // 196,608 total
    int d = idx / 98304, r = idx % 98304;
    int k2 = r / 768, col = r % 768;
    float lo = whh[d * 196608 + col * 256 + 2 * k2];
    float hi = whh[d * 196608 + col * 256 + 2 * k2 + 1];
    wpk[idx] = (unsigned int)f2bf(lo) | ((unsigned int)f2bf(hi) << 16);
}

// ---------------- GRU scan: streamed bf16 weights, 768 thr, scalar loads, unroll 4 ----------------
// grid = 2*S blocks; d = blk&1, s = blk>>1. Thread col owns gate-column col.
// Per step: 128 scalar uint loads (coalesced, L2-resident after step 0),
// h broadcast from LDS as float2. 12 waves/block hide L2 latency.
__global__ __launch_bounds__(768)
void gru_scan768(const unsigned short* __restrict__ gi_f, const unsigned short* __restrict__ gi_b,
                 const unsigned int* __restrict__ wpk, const float* __restrict__ bhh,
                 float* __restrict__ out) {
    int blk = blockIdx.x;
    int d = blk & 1, s = blk >> 1;
    const unsigned short* gi = (d ? gi_b : gi_f) + (size_t)s * LSEQ * H3;
    int col = threadIdx.x;          // 0..767
    const unsigned int* Wp = wpk + d * 98304 + col;
    float bcol = bhh[d * 768 + col];
    __shared__ float hs[HID];       // h vector (broadcast source)
    __shared__ float g[H3];         // gate pre-acts
    __shared__ float gn[HID];       // gi for n-gate
    if (col < HID) hs[col] = 0.f;
    float hreg = 0.f;               // thread col<256 owns h[col]
    __syncthreads();
    for (int step = 0; step < LSEQ; ++step) {
        int t = d ? (LSEQ - 1 - step) : step;
        float giv = bf2f(gi[(size_t)t * H3 + col]);   // issue early, overlaps dot
        float acc = bcol;
#pragma unroll 4
        for (int k2 = 0; k2 < 128; k2++) {
            float2 hv = *(const float2*)&hs[2 * k2];  // LDS broadcast
            unsigned int w = Wp[k2 * 768];            // coalesced 4B/lane
            acc += bflo(w) * hv.x + bfhi(w) * hv.y;
        }
        if (col < 512) g[col] = giv + acc;            // r,z pre-act
        else { g[col] = acc; gn[col - 512] = giv; }   // hn pre-act (w/ bhh_n), gi_n
        __syncthreads();
        if (col < HID) {
            float r = sigmoidf_(g[col]);
            float z = sigmoidf_(g[col + 256]);
            float n = tanhf(gn[col] + r * g[col + 512]);
            float hnew = (1.f - z) * n + z * hreg;
            hreg = hnew;
            hs[col] = hnew;
            out[((size_t)s * LSEQ + t) * H2 + d * HID + col] = hnew;
        }
        __syncthreads();
    }
}

// ---------------- bidaf helpers (fp32, unchanged) ----------------
__global__ void cwqw_kernel(const float* __restrict__ c, const float* __restrict__ q,
                            const float* __restrict__ w,
                            float* __restrict__ cw, float* __restrict__ qw) {
    int row = blockIdx.x;
    int lane = threadIdx.x;
    const float* src; const float* wv; float* dst; int r;
    if (row < 16384) { src = c; wv = w; dst = cw; r = row; }
    else { src = q; wv = w + 512; dst = qw; r = row - 16384; }
    const float* p = src + (size_t)r * H2;
    float acc = 0.f;
    for (int j = lane; j < H2; j += 64) acc += p[j] * wv[j];
    for (int off = 32; off; off >>= 1) acc += __shfl_down(acc, off);
    if (lane == 0) dst[r] = acc;
}

__global__ __launch_bounds__(256)
void smat_kernel(const float* __restrict__ c, const float* __restrict__ q,
                 const float* __restrict__ w2, const float* __restrict__ bvec,
                 const float* __restrict__ cw, const float* __restrict__ qw,
                 float* __restrict__ smat) {
    int b = blockIdx.z;
    int m0 = blockIdx.x * 64, n0 = blockIdx.y * 64;
    const float* A = c + (size_t)b * LSEQ * H2;
    const float* B = q + (size_t)b * LSEQ * H2;
    __shared__ float As[16][64];
    __shared__ float Bs[16][64];
    int tid = threadIdx.x;
    int lr = tid >> 2, lc = (tid & 3) * 4;
    int tm = (tid >> 4) * 4, tn = (tid & 15) * 4;
    float acc[4][4];
#pragma unroll
    for (int i = 0; i < 4; i++)
#pragma unroll
        for (int j = 0; j < 4; j++) acc[i][j] = 0.f;
    for (int k0 = 0; k0 < H2; k0 += 16) {
        float4 av = *(const float4*)(A + (size_t)(m0 + lr) * H2 + k0 + lc);
        float4 wv = *(const float4*)(w2 + k0 + lc);
        As[lc + 0][lr] = av.x * wv.x; As[lc + 1][lr] = av.y * wv.y;
        As[lc + 2][lr] = av.z * wv.z; As[lc + 3][lr] = av.w * wv.w;
        float4 bv = *(const float4*)(B + (size_t)(n0 + lr) * H2 + k0 + lc);
        Bs[lc + 0][lr] = bv.x; Bs[lc + 1][lr] = bv.y; Bs[lc + 2][lr] = bv.z; Bs[lc + 3][lr] = bv.w;
        __syncthreads();
#pragma unroll
        for (int kk = 0; kk < 16; kk++) {
            float4 a0 = *(const float4*)&As[kk][tm];
            float4 b0 = *(const float4*)&Bs[kk][tn];
            float a[4] = {a0.x, a0.y, a0.z, a0.w};
            float bb4[4] = {b0.x, b0.y, b0.z, b0.w};
#pragma unroll
            for (int i = 0; i < 4; i++)
#pragma unroll
                for (int j = 0; j < 4; j++) acc[i][j] += a[i] * bb4[j];
        }
        __syncthreads();
    }
    float bsum = bvec[0] + bvec[1] + bvec[2];
#pragma unroll
    for (int i = 0; i < 4; i++) {
        int m = m0 + tm + i;
        float cwv = cw[b * LSEQ + m];
        float4 o;
        o.x = acc[i][0] + cwv + qw[b * LSEQ + n0 + tn + 0] + bsum;
        o.y = acc[i][1] + cwv + qw[b * LSEQ + n0 + tn + 1] + bsum;
        o.z = acc[i][2] + cwv + qw[b * LSEQ + n0 + tn + 2] + bsum;
        o.w = acc[i][3] + cwv + qw[b * LSEQ + n0 + tn + 3] + bsum;
        *(float4*)(smat + ((size_t)b * LSEQ + m) * LSEQ + n0 + tn) = o;
    }
}

__global__ void softmax_kernel(float* __restrict__ smat, float* __restrict__ rowmax) {
    int row = blockIdx.x;
    int lane = threadIdx.x;
    float* p = smat + (size_t)row * LSEQ;
    float v[4];
    float mx = -1e30f;
#pragma unroll
    for (int j = 0; j < 4; j++) { v[j] = p[lane + j * 64]; mx = fmaxf(mx, v[j]); }
    for (int off = 32; off; off >>= 1) mx = fmaxf(mx, __shfl_down(mx, off));
    mx = __shfl(mx, 0);
    float sum = 0.f;
#pragma unroll
    for (int j = 0; j < 4; j++) { v[j] = __expf(v[j] - mx); sum += v[j]; }
    for (int off = 32; off; off >>= 1) sum += __shfl_down(sum, off);
    sum = __shfl(sum, 0);
    float inv = 1.f / sum;
#pragma unroll
    for (int j = 0; j < 4; j++) p[lane + j * 64] = v[j] * inv;
    if (lane == 0) rowmax[row] = mx;
}

__global__ void bb_kernel(const float* __restrict__ rowmax, float* __restrict__ bb) {
    int b = blockIdx.x; int t = threadIdx.x;
    __shared__ float red[256];
    float v = rowmax[b * LSEQ + t];
    red[t] = v; __syncthreads();
    for (int s = 128; s; s >>= 1) { if (t < s) red[t] = fmaxf(red[t], red[t + s]); __syncthreads(); }
    float mx = red[0]; __syncthreads();
    float e = __expf(v - mx);
    red[t] = e; __syncthreads();
    for (int s = 128; s; s >>= 1) { if (t < s) red[t] += red[t + s]; __syncthreads(); }
    bb[b * LSEQ + t] = e / red[0];
}

__global__ void q2c_kernel(const float* __restrict__ bb, const float* __restrict__ c,
                           float* __restrict__ q2c) {
    int b = blockIdx.x; int t = threadIdx.x;
    float a0 = 0.f, a1 = 0.f;
    for (int i = 0; i < LSEQ; i++) {
        float w = bb[b * LSEQ + i];
        const float* row = c + ((size_t)b * LSEQ + i) * H2;
        a0 += w * row[t];
        a1 += w * row[t + 256];
    }
    q2c[b * H2 + t] = a0;
    q2c[b * H2 + t + 256] = a1;
}

__global__ __launch_bounds__(256)
void c2q_fixup(const float* __restrict__ amat, const float* __restrict__ q,
               const float* __restrict__ c, float* __restrict__ att, int add) {
    int b = blockIdx.z;
    int m0 = blockIdx.x * 64, n0 = blockIdx.y * 64;
    const float* A = amat + (size_t)b * LSEQ * LSEQ;
    const float* B = q + (size_t)b * LSEQ * H2;
    __shared__ float As[16][64];
    __shared__ float Bs[16][64];
    int tid = threadIdx.x;
    int lr = tid >> 2, lc = (tid & 3) * 4;
    int br = tid >> 4, bc = (tid & 15) * 4;
    int tm = (tid >> 4) * 4, tn = (tid & 15) * 4;
    float acc[4][4];
#pragma unroll
    for (int i = 0; i < 4; i++)
#pragma unroll
        for (int j = 0; j < 4; j++) acc[i][j] = 0.f;
    for (int k0 = 0; k0 < LSEQ; k0 += 16) {
        float4 av = *(const float4*)(A + (size_t)(m0 + lr) * LSEQ + k0 + lc);
        As[lc + 0][lr] = av.x; As[lc + 1][lr] = av.y; As[lc + 2][lr] = av.z; As[lc + 3][lr] = av.w;
        float4 bv = *(const float4*)(B + (size_t)(k0 + br) * H2 + n0 + bc);
        *(float4*)&Bs[br][bc] = bv;
        __syncthreads();
#pragma unroll
        for (int kk = 0; kk < 16; kk++) {
            float4 a0 = *(const float4*)&As[kk][tm];
            float4 b0 = *(const float4*)&Bs[kk][tn];
            float a[4] = {a0.x, a0.y, a0.z, a0.w};
            float bb4[4] = {b0.x, b0.y, b0.z, b0.w};
#pragma unroll
            for (int i = 0; i < 4; i++)
#pragma unroll
                for (int j = 0; j < 4; j++) acc[i][j] += a[i] * bb4[j];
        }
        __syncthreads();
    }
#pragma unroll
    for (int i = 0; i < 4; i++) {
        int row = b * LSEQ + m0 + tm + i;
        float4 cv = *(const float4*)(c + (size_t)row * H2 + n0 + tn);
        float4 v1, v2;
        v1.x = fmaxf(acc[i][0], 0.f); v1.y = fmaxf(acc[i][1], 0.f);
        v1.z = fmaxf(acc[i][2], 0.f); v1.w = fmaxf(acc[i][3], 0.f);
        v2.x = fmaxf(cv.x * acc[i][0], 0.f); v2.y = fmaxf(cv.y * acc[i][1], 0.f);
        v2.z = fmaxf(cv.z * acc[i][2], 0.f); v2.w = fmaxf(cv.w * acc[i][3], 0.f);
        float* p1 = att + (size_t)row * H8 + 512 + n0 + tn;
        float* p2 = att + (size_t)row * H8 + 1024 + n0 + tn;
        if (add) {
            float4 o1 = *(float4*)p1, o2 = *(float4*)p2;
            o1.x += v1.x; o1.y += v1.y; o1.z += v1.z; o1.w += v1.w;
            o2.x += v2.x; o2.y += v2.y; o2.z += v2.z; o2.w += v2.w;
            *(float4*)p1 = o1; *(float4*)p2 = o2;
        } else {
            *(float4*)p1 = v1; *(float4*)p2 = v2;
        }
    }
}

__global__ void fixup03(const float* __restrict__ c, const float* __restrict__ q2c,
                        float* __restrict__ att, int add) {
    int row = blockIdx.x;
    int t = threadIdx.x;
    int b = row >> 8;
    float* o = att + (size_t)row * H8;
#pragma unroll
    for (int rep = 0; rep < 2; rep++) {
        int d = t + rep * 256;
        float cv = c[(size_t)row * H2 + d];
        float qv = q2c[b * H2 + d];
        float v0 = fmaxf(cv, 0.f);
        float v3 = fmaxf(cv * qv, 0.f);
        if (add) { o[d] += v0; o[d + 1536] += v3; }
        else     { o[d]  = v0; o[d + 1536]  = v3; }
    }
}

// ---------------- final rank reduce ----------------
__global__ void reduce1_kernel(const float* __restrict__ s, const float* __restrict__ rw,
                               float* __restrict__ part) {
    int bo = blockIdx.x;
    int p = blockIdx.y;
    int t = threadIdx.x;
    const float* s0 = s + (size_t)(2 * bo) * 524288;
    const float* s1 = s0 + 524288;
    size_t base = (size_t)p * 65536;
    float acc = 0.f;
    for (int j = t; j < 65536; j += 256) {
        size_t m = base + j;
        acc += rw[m] * fmaxf(s0[m], s1[m]);
    }
    __shared__ float red[256];
    red[t] = acc; __syncthreads();
    for (int ss = 128; ss; ss >>= 1) { if (t < ss) red[t] += red[t + ss]; __syncthreads(); }
    if (t == 0) part[bo * 8 + p] = red[0];
}

__global__ void reduce2_kernel(const float* __restrict__ part, const float* __restrict__ rb,
                               float* __restrict__ out) {
    int t = threadIdx.x;
    float a = rb[0];
    for (int p = 0; p < 8; p++) a += part[t * 8 + p];
    out[t] = a;
}

extern "C" void kernel_launch(void* const* d_in, const int* in_sizes, int n_in,
                              void* d_out, int out_size, void* d_ws, size_t ws_size,
                              hipStream_t stream) {
    const int* question = (const int*)d_in[0];
    const int* article  = (const int*)d_in[1];
    const float* emb    = (const float*)d_in[2];
    const float* g1_wih = (const float*)d_in[3];
    const float* g1_whh = (const float*)d_in[4];
    const float* g1_bih = (const float*)d_in[5];
    const float* g1_bhh = (const float*)d_in[6];
    const float* g2_wih = (const float*)d_in[7];
    const float* g2_whh = (const float*)d_in[8];
    const float* g2_bih = (const float*)d_in[9];
    const float* g2_bhh = (const float*)d_in[10];
    const float* b1_w   = (const float*)d_in[11];
    const float* b1_b   = (const float*)d_in[12];
    const float* b2_w   = (const float*)d_in[13];
    const float* b2_b   = (const float*)d_in[14];
    const float* rank_w = (const float*)d_in[15];
    const float* rank_b = (const float*)d_in[16];
    float* ws = (float*)d_ws;
    float* out = (float*)d_out;

    // ---- workspace layout (fp32 slots) — peak 224 MiB (proven budget) ----
    float*          HBUF  = ws;
    float*          ATT   = ws + 16777216;
    float*          XEMB  = ws + 16777216;
    unsigned short* GI1B  = (unsigned short*)(ws + 25165824);  // 2 dirs x 32768 x 768 bf16
    unsigned int*   WPK1  = (unsigned int*)(ws + 50331648);    // 196608 uints
    float*          SMAT1 = ws + 50331648;
    float*          S1    = ws + 54525952;
    unsigned short* GI2B  = (unsigned short*)ws;               // 2 dirs x 16384 x 768 bf16
    unsigned int*   WPK2  = (unsigned int*)(ws + 12582912);
    float*          AX2   = ws + 50331648;
    float*          SMAT2 = ws;
    float*          S2    = ws + 4194304;

    // 1. embed + pack whh1
    embed_kernel<<<32768, 256, 0, stream>>>(question, article, emb, XEMB);
    pack_whh_k2<<<768, 256, 0, stream>>>(g1_whh, WPK1);

    // 2. GRU1 input gates via MFMA: per dir, M=32768 N=768 K=256
    for (int d = 0; d < 2; d++) {
        gemm_mfma_bf16<<<dim3(256, 6), 256, 0, stream>>>(
            XEMB, g1_wih + (size_t)d * 196608, g1_bih + d * 768,
            GI1B + (size_t)d * 32768 * 768, 32768, 768, 256);
    }
    // 3. GRU1 scan: 256 blocks x 768 threads, streamed bf16 weights
    gru_scan768<<<256, 768, 0, stream>>>(GI1B, GI1B + (size_t)32768 * 768, WPK1, g1_bhh, HBUF);

    float* QH = HBUF;
    float* AH = HBUF + (size_t)64 * 256 * 512;

    // 4. BiDAF1: c=QH, q=AH -> ATT (set)
    {
        float* CW = S1, *QW = S1 + 16384, *RM = S1 + 32768, *BBv = S1 + 49152, *Q2C = S1 + 65536;
        cwqw_kernel<<<32768, 64, 0, stream>>>(QH, AH, b1_w, CW, QW);
        smat_kernel<<<dim3(4, 4, 64), 256, 0, stream>>>(QH, AH, b1_w + 1024, b1_b, CW, QW, SMAT1);
        softmax_kernel<<<16384, 64, 0, stream>>>(SMAT1, RM);
        bb_kernel<<<64, 256, 0, stream>>>(RM, BBv);
        q2c_kernel<<<64, 256, 0, stream>>>(BBv, QH, Q2C);
        fixup03<<<16384, 256, 0, stream>>>(QH, Q2C, ATT, 0);
        c2q_fixup<<<dim3(4, 8, 64), 256, 0, stream>>>(SMAT1, AH, QH, ATT, 0);
    }

    // pack whh2 (HBUF dead, region free)
    pack_whh_k2<<<768, 256, 0, stream>>>(g2_whh, WPK2);

    // 5. GRU2 input gates via MFMA: per dir, M=16384 N=768 K=2048
    for (int d = 0; d < 2; d++) {
        gemm_mfma_bf16<<<dim3(128, 6), 256, 0, stream>>>(
            ATT, g2_wih + (size_t)d * 1572864, g2_bih + d * 768,
            GI2B + (size_t)d * 16384 * 768, 16384, 768, 2048);
    }
    // 6. GRU2 scan: 128 blocks x 768 threads
    gru_scan768<<<128, 768, 0, stream>>>(GI2B, GI2B + (size_t)16384 * 768, WPK2, g2_bhh, AX2);

    // 7. BiDAF2: c=q=AX2 -> ATT (accumulate)
    {
        float* CW = S2, *QW = S2 + 16384, *RM = S2 + 32768, *BBv = S2 + 49152, *Q2C = S2 + 65536;
        cwqw_kernel<<<32768, 64, 0, stream>>>(AX2, AX2, b2_w, CW, QW);
        smat_kernel<<<dim3(4, 4, 64), 256, 0, stream>>>(AX2, AX2, b2_w + 1024, b2_b, CW, QW, SMAT2);
        softmax_kernel<<<16384, 64, 0, stream>>>(SMAT2, RM);
        bb_kernel<<<64, 256, 0, stream>>>(RM, BBv);
        q2c_kernel<<<64, 256, 0, stream>>>(BBv, AX2, Q2C);
        fixup03<<<16384, 256, 0, stream>>>(AX2, Q2C, ATT, 1);
        c2q_fixup<<<dim3(4, 8, 64), 256, 0, stream>>>(SMAT2, AX2, AX2, ATT, 1);
    }

    // 8. rank reduce
    float* PART = S2 + 98304;
    reduce1_kernel<<<dim3(32, 8), 256, 0, stream>>>(ATT, rank_w, PART);
    reduce2_kernel<<<1, 32, 0, stream>>>(PART, rank_b, out);
}

// Round 10
// 3149.937 us; speedup vs baseline: 5.0773x; 1.3331x over previous
//
#include <hip/hip_runtime.h>
#include <math.h>

#define LSEQ 256
#define HID 256
#define H2 512
#define H3 768
#define H8 2048

typedef __attribute__((ext_vector_type(8))) short short8;
typedef __attribute__((ext_vector_type(4))) float floatx4;
typedef __attribute__((ext_vector_type(2))) float fx2;

__device__ __forceinline__ float sigmoidf_(float x) { return 1.f / (1.f + __expf(-x)); }
__device__ __forceinline__ unsigned short f2bf(float f) {
    unsigned int u = __float_as_uint(f);
    u = (u + 0x7FFFu + ((u >> 16) & 1u)) >> 16;
    return (unsigned short)u;
}
__device__ __forceinline__ float bf2f(unsigned short h) {
    return __uint_as_float(((unsigned int)h) << 16);
}
__device__ __forceinline__ float bflo(unsigned int w) {
    return __uint_as_float(w << 16);
}
__device__ __forceinline__ float bfhi(unsigned int w) {
    return __uint_as_float(w & 0xFFFF0000u);
}

// ---------------- embed ----------------
__global__ void embed_kernel(const int* __restrict__ question,
                             const int* __restrict__ article,
                             const float* __restrict__ emb,
                             float* __restrict__ xemb) {
    int gid = blockIdx.x * 256 + threadIdx.x;   // 128*256*256
    int d = gid & 255;
    int rl = gid >> 8;
    int l = rl & 255;
    int stream = rl >> 8;
    int id;
    if (stream < 64) {
        int b = stream >> 3, o = (stream & 7) >> 1;
        id = question[(b * 4 + o) * 256 + l];
    } else {
        id = article[(stream - 64) * 256 + l];
    }
    xemb[(size_t)gid] = emb[(size_t)id * 256 + d];
}

// ---------------- MFMA bf16 GEMM ----------------
__global__ __launch_bounds__(256)
void gemm_mfma_bf16(const float* __restrict__ A, const float* __restrict__ B,
                    const float* __restrict__ bias, unsigned short* __restrict__ C,
                    int M, int N, int K) {
    __shared__ unsigned short At[128][40];
    __shared__ unsigned short Bt[128][40];
    int tid = threadIdx.x;
    int m0 = blockIdx.x * 128, n0 = blockIdx.y * 128;
    int l = tid & 63, w = tid >> 6;
    int wm = (w & 1) * 64, wn = (w >> 1) * 64;
    int lr = l & 15, koff = (l >> 4) * 8;
    int srow = tid >> 1, scol = (tid & 1) * 16;
    floatx4 acc[4][4];
#pragma unroll
    for (int i = 0; i < 4; i++)
#pragma unroll
        for (int j = 0; j < 4; j++) acc[i][j] = (floatx4){0.f, 0.f, 0.f, 0.f};
    for (int k0 = 0; k0 < K; k0 += 32) {
        const float* ap = A + (size_t)(m0 + srow) * K + k0 + scol;
        const float* bp = B + (size_t)(n0 + srow) * K + k0 + scol;
        float av[16], bv[16];
        *(float4*)&av[0]  = *(const float4*)(ap);
        *(float4*)&av[4]  = *(const float4*)(ap + 4);
        *(float4*)&av[8]  = *(const float4*)(ap + 8);
        *(float4*)&av[12] = *(const float4*)(ap + 12);
        *(float4*)&bv[0]  = *(const float4*)(bp);
        *(float4*)&bv[4]  = *(const float4*)(bp + 4);
        *(float4*)&bv[8]  = *(const float4*)(bp + 8);
        *(float4*)&bv[12] = *(const float4*)(bp + 12);
        unsigned int aw[8], bw[8];
#pragma unroll
        for (int i = 0; i < 8; i++) {
            aw[i] = (unsigned int)f2bf(av[2 * i]) | ((unsigned int)f2bf(av[2 * i + 1]) << 16);
            bw[i] = (unsigned int)f2bf(bv[2 * i]) | ((unsigned int)f2bf(bv[2 * i + 1]) << 16);
        }
        __syncthreads();
        *(uint4*)&At[srow][scol]     = *(uint4*)&aw[0];
        *(uint4*)&At[srow][scol + 8] = *(uint4*)&aw[4];
        *(uint4*)&Bt[srow][scol]     = *(uint4*)&bw[0];
        *(uint4*)&Bt[srow][scol + 8] = *(uint4*)&bw[4];
        __syncthreads();
        short8 af[4], bf[4];
#pragma unroll
        for (int i = 0; i < 4; i++) {
            af[i] = *(const short8*)&At[wm + i * 16 + lr][koff];
            bf[i] = *(const short8*)&Bt[wn + i * 16 + lr][koff];
        }
#pragma unroll
        for (int i = 0; i < 4; i++)
#pragma unroll
            for (int j = 0; j < 4; j++)
                acc[i][j] = __builtin_amdgcn_mfma_f32_16x16x32_bf16(af[i], bf[j], acc[i][j], 0, 0, 0);
    }
    int quad = l >> 4;
#pragma unroll
    for (int i = 0; i < 4; i++) {
#pragma unroll
        for (int j = 0; j < 4; j++) {
            int n = n0 + wn + j * 16 + lr;
            float bs = bias[n];
#pragma unroll
            for (int r = 0; r < 4; r++) {
                int m = m0 + wm + i * 16 + quad * 4 + r;
                C[(size_t)m * N + n] = f2bf(acc[i][j][r] + bs);
            }
        }
    }
}

// ---------------- whh pack to [d][chunk(32)][col(768)][i(4)] of bf16 pairs ----------------
// pair p = 4c+i covers whh k = 2p, 2p+1 for column col. One uint4 per (c,col).
__global__ void pack_whh4(const float* __restrict__ whh, unsigned int* __restrict__ wq) {
    int idx = blockIdx.x * 256 + threadIdx.x;   // 196,608 total
    int d = idx / 98304, r = idx % 98304;
    int c = r / 3072, r2 = r % 3072;
    int col = r2 >> 2, i = r2 & 3;
    int p = 4 * c + i;
    float lo = whh[d * 196608 + col * 256 + 2 * p];
    float hi = whh[d * 196608 + col * 256 + 2 * p + 1];
    wq[idx] = (unsigned int)f2bf(lo) | ((unsigned int)f2bf(hi) << 16);
}

// ---------------- GRU scan: streamed bf16 weights, uint4 loads, packed-f32 FMA ----------------
// grid = 2*S blocks; d = blk&1, s = blk>>1. Thread col owns gate-column col.
// Per step: 32 uint4 loads (16B/lane coalesced, L2-resident), h broadcast from LDS.
// unroll 2 keeps <=2 uint4 in flight (R8 lesson: full unroll => load hoist => spill).
__global__ __launch_bounds__(768)
void gru_scan768(const unsigned short* __restrict__ gi_f, const unsigned short* __restrict__ gi_b,
                 const unsigned int* __restrict__ wpk, const float* __restrict__ bhh,
                 float* __restrict__ out) {
    int blk = blockIdx.x;
    int d = blk & 1, s = blk >> 1;
    const unsigned short* gi = (d ? gi_b : gi_f) + (size_t)s * LSEQ * H3;
    int col = threadIdx.x;          // 0..767
    const uint4* Wq = (const uint4*)wpk + (size_t)d * 24576 + col;   // [c][col] stride 768
    float bcol = bhh[d * 768 + col];
    __shared__ float hs[HID];       // h vector (broadcast source)
    __shared__ float g[H3];         // gate pre-acts
    __shared__ float gn[HID];       // gi for n-gate
    if (col < HID) hs[col] = 0.f;
    float hreg = 0.f;               // thread col<256 owns h[col]
    __syncthreads();
    const float4* hs4 = (const float4*)hs;
    for (int step = 0; step < LSEQ; ++step) {
        int t = d ? (LSEQ - 1 - step) : step;
        float giv = bf2f(gi[(size_t)t * H3 + col]);   // issue early, overlaps dot
        fx2 acc2 = {bcol, 0.f};
#pragma unroll 2
        for (int c = 0; c < 32; c++) {
            uint4 w = Wq[c * 768];                    // 4 bf16-pairs: k = 8c..8c+7
            float4 h0 = hs4[2 * c];
            float4 h1 = hs4[2 * c + 1];
            fx2 w0 = {bflo(w.x), bfhi(w.x)};
            fx2 w1 = {bflo(w.y), bfhi(w.y)};
            fx2 w2 = {bflo(w.z), bfhi(w.z)};
            fx2 w3 = {bflo(w.w), bfhi(w.w)};
            acc2 += w0 * (fx2){h0.x, h0.y};
            acc2 += w1 * (fx2){h0.z, h0.w};
            acc2 += w2 * (fx2){h1.x, h1.y};
            acc2 += w3 * (fx2){h1.z, h1.w};
        }
        float acc = acc2.x + acc2.y;
        if (col < 512) g[col] = giv + acc;            // r,z pre-act
        else { g[col] = acc; gn[col - 512] = giv; }   // hn pre-act (w/ bhh_n), gi_n
        __syncthreads();
        if (col < HID) {
            float r = sigmoidf_(g[col]);
            float z = sigmoidf_(g[col + 256]);
            float n = tanhf(gn[col] + r * g[col + 512]);
            float hnew = (1.f - z) * n + z * hreg;
            hreg = hnew;
            hs[col] = hnew;
            out[((size_t)s * LSEQ + t) * H2 + d * HID + col] = hnew;
        }
        __syncthreads();
    }
}

// ---------------- bidaf helpers (fp32, unchanged) ----------------
__global__ void cwqw_kernel(const float* __restrict__ c, const float* __restrict__ q,
                            const float* __restrict__ w,
                            float* __restrict__ cw, float* __restrict__ qw) {
    int row = blockIdx.x;
    int lane = threadIdx.x;
    const float* src; const float* wv; float* dst; int r;
    if (row < 16384) { src = c; wv = w; dst = cw; r = row; }
    else { src = q; wv = w + 512; dst = qw; r = row - 16384; }
    const float* p = src + (size_t)r * H2;
    float acc = 0.f;
    for (int j = lane; j < H2; j += 64) acc += p[j] * wv[j];
    for (int off = 32; off; off >>= 1) acc += __shfl_down(acc, off);
    if (lane == 0) dst[r] = acc;
}

__global__ __launch_bounds__(256)
void smat_kernel(const float* __restrict__ c, const float* __restrict__ q,
                 const float* __restrict__ w2, const float* __restrict__ bvec,
                 const float* __restrict__ cw, const float* __restrict__ qw,
                 float* __restrict__ smat) {
    int b = blockIdx.z;
    int m0 = blockIdx.x * 64, n0 = blockIdx.y * 64;
    const float* A = c + (size_t)b * LSEQ * H2;
    const float* B = q + (size_t)b * LSEQ * H2;
    __shared__ float As[16][64];
    __shared__ float Bs[16][64];
    int tid = threadIdx.x;
    int lr = tid >> 2, lc = (tid & 3) * 4;
    int tm = (tid >> 4) * 4, tn = (tid & 15) * 4;
    float acc[4][4];
#pragma unroll
    for (int i = 0; i < 4; i++)
#pragma unroll
        for (int j = 0; j < 4; j++) acc[i][j] = 0.f;
    for (int k0 = 0; k0 < H2; k0 += 16) {
        float4 av = *(const float4*)(A + (size_t)(m0 + lr) * H2 + k0 + lc);
        float4 wv = *(const float4*)(w2 + k0 + lc);
        As[lc + 0][lr] = av.x * wv.x; As[lc + 1][lr] = av.y * wv.y;
        As[lc + 2][lr] = av.z * wv.z; As[lc + 3][lr] = av.w * wv.w;
        float4 bv = *(const float4*)(B + (size_t)(n0 + lr) * H2 + k0 + lc);
        Bs[lc + 0][lr] = bv.x; Bs[lc + 1][lr] = bv.y; Bs[lc + 2][lr] = bv.z; Bs[lc + 3][lr] = bv.w;
        __syncthreads();
#pragma unroll
        for (int kk = 0; kk < 16; kk++) {
            float4 a0 = *(const float4*)&As[kk][tm];
            float4 b0 = *(const float4*)&Bs[kk][tn];
            float a[4] = {a0.x, a0.y, a0.z, a0.w};
            float bb4[4] = {b0.x, b0.y, b0.z, b0.w};
#pragma unroll
            for (int i = 0; i < 4; i++)
#pragma unroll
                for (int j = 0; j < 4; j++) acc[i][j] += a[i] * bb4[j];
        }
        __syncthreads();
    }
    float bsum = bvec[0] + bvec[1] + bvec[2];
#pragma unroll
    for (int i = 0; i < 4; i++) {
        int m = m0 + tm + i;
        float cwv = cw[b * LSEQ + m];
        float4 o;
        o.x = acc[i][0] + cwv + qw[b * LSEQ + n0 + tn + 0] + bsum;
        o.y = acc[i][1] + cwv + qw[b * LSEQ + n0 + tn + 1] + bsum;
        o.z = acc[i][2] + cwv + qw[b * LSEQ + n0 + tn + 2] + bsum;
        o.w = acc[i][3] + cwv + qw[b * LSEQ + n0 + tn + 3] + bsum;
        *(float4*)(smat + ((size_t)b * LSEQ + m) * LSEQ + n0 + tn) = o;
    }
}

__global__ void softmax_kernel(float* __restrict__ smat, float* __restrict__ rowmax) {
    int row = blockIdx.x;
    int lane = threadIdx.x;
    float* p = smat + (size_t)row * LSEQ;
    float v[4];
    float mx = -1e30f;
#pragma unroll
    for (int j = 0; j < 4; j++) { v[j] = p[lane + j * 64]; mx = fmaxf(mx, v[j]); }
    for (int off = 32; off; off >>= 1) mx = fmaxf(mx, __shfl_down(mx, off));
    mx = __shfl(mx, 0);
    float sum = 0.f;
#pragma unroll
    for (int j = 0; j < 4; j++) { v[j] = __expf(v[j] - mx); sum += v[j]; }
    for (int off = 32; off; off >>= 1) sum += __shfl_down(sum, off);
    sum = __shfl(sum, 0);
    float inv = 1.f / sum;
#pragma unroll
    for (int j = 0; j < 4; j++) p[lane + j * 64] = v[j] * inv;
    if (lane == 0) rowmax[row] = mx;
}

__global__ void bb_kernel(const float* __restrict__ rowmax, float* __restrict__ bb) {
    int b = blockIdx.x; int t = threadIdx.x;
    __shared__ float red[256];
    float v = rowmax[b * LSEQ + t];
    red[t] = v; __syncthreads();
    for (int s = 128; s; s >>= 1) { if (t < s) red[t] = fmaxf(red[t], red[t + s]); __syncthreads(); }
    float mx = red[0]; __syncthreads();
    float e = __expf(v - mx);
    red[t] = e; __syncthreads();
    for (int s = 128; s; s >>= 1) { if (t < s) red[t] += red[t + s]; __syncthreads(); }
    bb[b * LSEQ + t] = e / red[0];
}

__global__ void q2c_kernel(const float* __restrict__ bb, const float* __restrict__ c,
                           float* __restrict__ q2c) {
    int b = blockIdx.x; int t = threadIdx.x;
    float a0 = 0.f, a1 = 0.f;
    for (int i = 0; i < LSEQ; i++) {
        float w = bb[b * LSEQ + i];
        const float* row = c + ((size_t)b * LSEQ + i) * H2;
        a0 += w * row[t];
        a1 += w * row[t + 256];
    }
    q2c[b * H2 + t] = a0;
    q2c[b * H2 + t + 256] = a1;
}

__global__ __launch_bounds__(256)
void c2q_fixup(const float* __restrict__ amat, const float* __restrict__ q,
               const float* __restrict__ c, float* __restrict__ att, int add) {
    int b = blockIdx.z;
    int m0 = blockIdx.x * 64, n0 = blockIdx.y * 64;
    const float* A = amat + (size_t)b * LSEQ * LSEQ;
    const float* B = q + (size_t)b * LSEQ * H2;
    __shared__ float As[16][64];
    __shared__ float Bs[16][64];
    int tid = threadIdx.x;
    int lr = tid >> 2, lc = (tid & 3) * 4;
    int br = tid >> 4, bc = (tid & 15) * 4;
    int tm = (tid >> 4) * 4, tn = (tid & 15) * 4;
    float acc[4][4];
#pragma unroll
    for (int i = 0; i < 4; i++)
#pragma unroll
        for (int j = 0; j < 4; j++) acc[i][j] = 0.f;
    for (int k0 = 0; k0 < LSEQ; k0 += 16) {
        float4 av = *(const float4*)(A + (size_t)(m0 + lr) * LSEQ + k0 + lc);
        As[lc + 0][lr] = av.x; As[lc + 1][lr] = av.y; As[lc + 2][lr] = av.z; As[lc + 3][lr] = av.w;
        float4 bv = *(const float4*)(B + (size_t)(k0 + br) * H2 + n0 + bc);
        *(float4*)&Bs[br][bc] = bv;
        __syncthreads();
#pragma unroll
        for (int kk = 0; kk < 16; kk++) {
            float4 a0 = *(const float4*)&As[kk][tm];
            float4 b0 = *(const float4*)&Bs[kk][tn];
            float a[4] = {a0.x, a0.y, a0.z, a0.w};
            float bb4[4] = {b0.x, b0.y, b0.z, b0.w};
#pragma unroll
            for (int i = 0; i < 4; i++)
#pragma unroll
                for (int j = 0; j < 4; j++) acc[i][j] += a[i] * bb4[j];
        }
        __syncthreads();
    }
#pragma unroll
    for (int i = 0; i < 4; i++) {
        int row = b * LSEQ + m0 + tm + i;
        float4 cv = *(const float4*)(c + (size_t)row * H2 + n0 + tn);
        float4 v1, v2;
        v1.x = fmaxf(acc[i][0], 0.f); v1.y = fmaxf(acc[i][1], 0.f);
        v1.z = fmaxf(acc[i][2], 0.f); v1.w = fmaxf(acc[i][3], 0.f);
        v2.x = fmaxf(cv.x * acc[i][0], 0.f); v2.y = fmaxf(cv.y * acc[i][1], 0.f);
        v2.z = fmaxf(cv.z * acc[i][2], 0.f); v2.w = fmaxf(cv.w * acc[i][3], 0.f);
        float* p1 = att + (size_t)row * H8 + 512 + n0 + tn;
        float* p2 = att + (size_t)row * H8 + 1024 + n0 + tn;
        if (add) {
            float4 o1 = *(float4*)p1, o2 = *(float4*)p2;
            o1.x += v1.x; o1.y += v1.y; o1.z += v1.z; o1.w += v1.w;
            o2.x += v2.x; o2.y += v2.y; o2.z += v2.z; o2.w += v2.w;
            *(float4*)p1 = o1; *(float4*)p2 = o2;
        } else {
            *(float4*)p1 = v1; *(float4*)p2 = v2;
        }
    }
}

__global__ void fixup03(const float* __restrict__ c, const float* __restrict__ q2c,
                        float* __restrict__ att, int add) {
    int row = blockIdx.x;
    int t = threadIdx.x;
    int b = row >> 8;
    float* o = att + (size_t)row * H8;
#pragma unroll
    for (int rep = 0; rep < 2; rep++) {
        int d = t + rep * 256;
        float cv = c[(size_t)row * H2 + d];
        float qv = q2c[b * H2 + d];
        float v0 = fmaxf(cv, 0.f);
        float v3 = fmaxf(cv * qv, 0.f);
        if (add) { o[d] += v0; o[d + 1536] += v3; }
        else     { o[d]  = v0; o[d + 1536]  = v3; }
    }
}

// ---------------- final rank reduce ----------------
__global__ void reduce1_kernel(const float* __restrict__ s, const float* __restrict__ rw,
                               float* __restrict__ part) {
    int bo = blockIdx.x;
    int p = blockIdx.y;
    int t = threadIdx.x;
    const float* s0 = s + (size_t)(2 * bo) * 524288;
    const float* s1 = s0 + 524288;
    size_t base = (size_t)p * 65536;
    float acc = 0.f;
    for (int j = t; j < 65536; j += 256) {
        size_t m = base + j;
        acc += rw[m] * fmaxf(s0[m], s1[m]);
    }
    __shared__ float red[256];
    red[t] = acc; __syncthreads();
    for (int ss = 128; ss; ss >>= 1) { if (t < ss) red[t] += red[t + ss]; __syncthreads(); }
    if (t == 0) part[bo * 8 + p] = red[0];
}

__global__ void reduce2_kernel(const float* __restrict__ part, const float* __restrict__ rb,
                               float* __restrict__ out) {
    int t = threadIdx.x;
    float a = rb[0];
    for (int p = 0; p < 8; p++) a += part[t * 8 + p];
    out[t] = a;
}

extern "C" void kernel_launch(void* const* d_in, const int* in_sizes, int n_in,
                              void* d_out, int out_size, void* d_ws, size_t ws_size,
                              hipStream_t stream) {
    const int* question = (const int*)d_in[0];
    const int* article  = (const int*)d_in[1];
    const float* emb    = (const float*)d_in[2];
    const float* g1_wih = (const float*)d_in[3];
    const float* g1_whh = (const float*)d_in[4];
    const float* g1_bih = (const float*)d_in[5];
    const float* g1_bhh = (const float*)d_in[6];
    const float* g2_wih = (const float*)d_in[7];
    const float* g2_whh = (const float*)d_in[8];
    const float* g2_bih = (const float*)d_in[9];
    const float* g2_bhh = (const float*)d_in[10];
    const float* b1_w   = (const float*)d_in[11];
    const float* b1_b   = (const float*)d_in[12];
    const float* b2_w   = (const float*)d_in[13];
    const float* b2_b   = (const float*)d_in[14];
    const float* rank_w = (const float*)d_in[15];
    const float* rank_b = (const float*)d_in[16];
    float* ws = (float*)d_ws;
    float* out = (float*)d_out;

    // ---- workspace layout (fp32 slots) — peak 224 MiB (proven budget) ----
    float*          HBUF  = ws;
    float*          ATT   = ws + 16777216;
    float*          XEMB  = ws + 16777216;
    unsigned short* GI1B  = (unsigned short*)(ws + 25165824);  // 2 dirs x 32768 x 768 bf16
    unsigned int*   WPK1  = (unsigned int*)(ws + 50331648);    // 196608 uints
    float*          SMAT1 = ws + 50331648;
    float*          S1    = ws + 54525952;
    unsigned short* GI2B  = (unsigned short*)ws;               // 2 dirs x 16384 x 768 bf16
    unsigned int*   WPK2  = (unsigned int*)(ws + 12582912);
    float*          AX2   = ws + 50331648;
    float*          SMAT2 = ws;
    float*          S2    = ws + 4194304;

    // 1. embed + pack whh1
    embed_kernel<<<32768, 256, 0, stream>>>(question, article, emb, XEMB);
    pack_whh4<<<768, 256, 0, stream>>>(g1_whh, WPK1);

    // 2. GRU1 input gates via MFMA: per dir, M=32768 N=768 K=256
    for (int d = 0; d < 2; d++) {
        gemm_mfma_bf16<<<dim3(256, 6), 256, 0, stream>>>(
            XEMB, g1_wih + (size_t)d * 196608, g1_bih + d * 768,
            GI1B + (size_t)d * 32768 * 768, 32768, 768, 256);
    }
    // 3. GRU1 scan: 256 blocks x 768 threads, streamed bf16 weights (uint4 + pk_fma)
    gru_scan768<<<256, 768, 0, stream>>>(GI1B, GI1B + (size_t)32768 * 768, WPK1, g1_bhh, HBUF);

    float* QH = HBUF;
    float* AH = HBUF + (size_t)64 * 256 * 512;

    // 4. BiDAF1: c=QH, q=AH -> ATT (set)
    {
        float* CW = S1, *QW = S1 + 16384, *RM = S1 + 32768, *BBv = S1 + 49152, *Q2C = S1 + 65536;
        cwqw_kernel<<<32768, 64, 0, stream>>>(QH, AH, b1_w, CW, QW);
        smat_kernel<<<dim3(4, 4, 64), 256, 0, stream>>>(QH, AH, b1_w + 1024, b1_b, CW, QW, SMAT1);
        softmax_kernel<<<16384, 64, 0, stream>>>(SMAT1, RM);
        bb_kernel<<<64, 256, 0, stream>>>(RM, BBv);
        q2c_kernel<<<64, 256, 0, stream>>>(BBv, QH, Q2C);
        fixup03<<<16384, 256, 0, stream>>>(QH, Q2C, ATT, 0);
        c2q_fixup<<<dim3(4, 8, 64), 256, 0, stream>>>(SMAT1, AH, QH, ATT, 0);
    }

    // pack whh2 (HBUF dead, region free)
    pack_whh4<<<768, 256, 0, stream>>>(g2_whh, WPK2);

    // 5. GRU2 input gates via MFMA: per dir, M=16384 N=768 K=2048
    for (int d = 0; d < 2; d++) {
        gemm_mfma_bf16<<<dim3(128, 6), 256, 0, stream>>>(
            ATT, g2_wih + (size_t)d * 1572864, g2_bih + d * 768,
            GI2B + (size_t)d * 16384 * 768, 16384, 768, 2048);
    }
    // 6. GRU2 scan: 128 blocks x 768 threads
    gru_scan768<<<128, 768, 0, stream>>>(GI2B, GI2B + (size_t)16384 * 768, WPK2, g2_bhh, AX2);

    // 7. BiDAF2: c=q=AX2 -> ATT (accumulate)
    {
        float* CW = S2, *QW = S2 + 16384, *RM = S2 + 32768, *BBv = S2 + 49152, *Q2C = S2 + 65536;
        cwqw_kernel<<<32768, 64, 0, stream>>>(AX2, AX2, b2_w, CW, QW);
        smat_kernel<<<dim3(4, 4, 64), 256, 0, stream>>>(AX2, AX2, b2_w + 1024, b2_b, CW, QW, SMAT2);
        softmax_kernel<<<16384, 64, 0, stream>>>(SMAT2, RM);
        bb_kernel<<<64, 256, 0, stream>>>(RM, BBv);
        q2c_kernel<<<64, 256, 0, stream>>>(BBv, AX2, Q2C);
        fixup03<<<16384, 256, 0, stream>>>(AX2, Q2C, ATT, 1);
        c2q_fixup<<<dim3(4, 8, 64), 256, 0, stream>>>(SMAT2, AX2, AX2, ATT, 1);
    }

    // 8. rank reduce
    float* PART = S2 + 98304;
    reduce1_kernel<<<dim3(32, 8), 256, 0, stream>>>(ATT, rank_w, PART);
    reduce2_kernel<<<1, 32, 0, stream>>>(PART, rank_b, out);
}